// Round 1
// baseline (220.104 us; speedup 1.0000x reference)
//
#include <hip/hip_runtime.h>

typedef float f4 __attribute__((ext_vector_type(4)));

#define TILE 64
#define BK 16

// C[M,N] = A[M,K] @ W[N,K]^T + bias + bias2   (row-major, W row-stride = ldw)
__global__ __launch_bounds__(256) void gemm_nt_kernel(
    const float* __restrict__ A, int M, int K,
    const float* __restrict__ W, int ldw,
    const float* __restrict__ bias, const float* __restrict__ bias2,
    float* __restrict__ C, int N)
{
    __shared__ float As[BK][TILE + 4];
    __shared__ float Bs[BK][TILE + 4];

    const int tid = threadIdx.x;
    const int tx  = tid & 15;       // n-quad selector
    const int ty  = tid >> 4;       // m-quad selector
    const int row = tid >> 2;       // 0..63: load row
    const int kq  = (tid & 3) * 4;  // k offset within tile: 0,4,8,12

    const int m0 = blockIdx.x * TILE;
    const int n0 = blockIdx.y * TILE;

    const float* Arow = A + (size_t)(m0 + row) * K + kq;
    const float* Wrow = W + (size_t)(n0 + row) * ldw + kq;

    float acc[4][4];
    #pragma unroll
    for (int i = 0; i < 4; ++i)
        #pragma unroll
        for (int j = 0; j < 4; ++j) acc[i][j] = 0.f;

    for (int k0 = 0; k0 < K; k0 += BK) {
        f4 av = *(const f4*)(Arow + k0);
        f4 wv = *(const f4*)(Wrow + k0);
        As[kq + 0][row] = av.x; As[kq + 1][row] = av.y;
        As[kq + 2][row] = av.z; As[kq + 3][row] = av.w;
        Bs[kq + 0][row] = wv.x; Bs[kq + 1][row] = wv.y;
        Bs[kq + 2][row] = wv.z; Bs[kq + 3][row] = wv.w;
        __syncthreads();
        #pragma unroll
        for (int k = 0; k < BK; ++k) {
            f4 a = *(const f4*)&As[k][ty * 4];
            f4 b = *(const f4*)&Bs[k][tx * 4];
            acc[0][0] += a.x * b.x; acc[0][1] += a.x * b.y;
            acc[0][2] += a.x * b.z; acc[0][3] += a.x * b.w;
            acc[1][0] += a.y * b.x; acc[1][1] += a.y * b.y;
            acc[1][2] += a.y * b.z; acc[1][3] += a.y * b.w;
            acc[2][0] += a.z * b.x; acc[2][1] += a.z * b.y;
            acc[2][2] += a.z * b.z; acc[2][3] += a.z * b.w;
            acc[3][0] += a.w * b.x; acc[3][1] += a.w * b.y;
            acc[3][2] += a.w * b.z; acc[3][3] += a.w * b.w;
        }
        __syncthreads();
    }

    const int m = m0 + ty * 4;
    const int n = n0 + tx * 4;
    float bv[4];
    #pragma unroll
    for (int j = 0; j < 4; ++j) {
        float b = bias  ? bias[n + j]  : 0.f;
        float b2 = bias2 ? bias2[n + j] : 0.f;
        bv[j] = b + b2;
    }
    #pragma unroll
    for (int i = 0; i < 4; ++i) {
        f4 o = { acc[i][0] + bv[0], acc[i][1] + bv[1],
                 acc[i][2] + bv[2], acc[i][3] + bv[3] };
        *(f4*)&C[(size_t)(m + i) * N + n] = o;
    }
}

// out[(bt)*U + u][v] = X[bt][v] + Y[b*U+u][v]; V=1024, Vq=256 float4/row.
__global__ __launch_bounds__(256) void bcast_kernel(
    const float* __restrict__ X, const float* __restrict__ Y,
    float* __restrict__ out, int T, int U)
{
    const int Vq  = 256;           // 1024 / 4
    const int bt  = blockIdx.x;    // 0 .. B*T-1
    const int b   = bt / T;
    const int tid = threadIdx.x;   // 0..255

    const f4* X4 = (const f4*)X;
    const f4* Y4 = (const f4*)Y + (size_t)b * U * Vq;
    f4* O4 = (f4*)out + (size_t)bt * U * Vq;

    f4 x = X4[(size_t)bt * Vq + tid];
    #pragma unroll 4
    for (int u = 0; u < U; ++u) {
        f4 y = Y4[u * Vq + tid];
        f4 r = { x.x + y.x, x.y + y.y, x.z + y.z, x.w + y.w };
        __builtin_nontemporal_store(r, &O4[u * Vq + tid]);
    }
}

extern "C" void kernel_launch(void* const* d_in, const int* in_sizes, int n_in,
                              void* d_out, int out_size, void* d_ws, size_t ws_size,
                              hipStream_t stream) {
    (void)in_sizes; (void)n_in; (void)out_size; (void)ws_size;

    const int B = 8, T = 256, U = 64;
    const int ENC = 512, DEC = 640, J = 512, V = 1024;

    const float* enc    = (const float*)d_in[0]; // (B*T, ENC)
    const float* pred   = (const float*)d_in[1]; // (B*U, DEC)
    const float* W_enc  = (const float*)d_in[2]; // (J, ENC)
    const float* b_enc  = (const float*)d_in[3]; // (J)
    const float* W_pred = (const float*)d_in[4]; // (J, DEC)
    const float* b_pred = (const float*)d_in[5]; // (J)
    const float* W_out  = (const float*)d_in[6]; // (V, 2J)
    const float* b_out  = (const float*)d_in[7]; // (V)
    float* out = (float*)d_out;

    float* ws   = (float*)d_ws;
    float* ws_e = ws;                               // (B*T, J)   = 2048x512
    float* ws_p = ws_e + (size_t)B * T * J;         // (B*U, J)   = 512x512
    float* ws_X = ws_p + (size_t)B * U * J;         // (B*T, V)   = 2048x1024
    float* ws_Y = ws_X + (size_t)B * T * V;         // (B*U, V)   = 512x1024

    const int MT = B * T;   // 2048
    const int MU = B * U;   // 512

    // e = enc @ W_enc^T + b_enc
    gemm_nt_kernel<<<dim3(MT / TILE, J / TILE), 256, 0, stream>>>(
        enc, MT, ENC, W_enc, ENC, b_enc, nullptr, ws_e, J);
    // p = pred @ W_pred^T + b_pred
    gemm_nt_kernel<<<dim3(MU / TILE, J / TILE), 256, 0, stream>>>(
        pred, MU, DEC, W_pred, DEC, b_pred, nullptr, ws_p, J);
    // X = e @ W1^T + b_out   (W1 = W_out[:, :J], row stride 2J)
    gemm_nt_kernel<<<dim3(MT / TILE, V / TILE), 256, 0, stream>>>(
        ws_e, MT, J, W_out, 2 * J, b_out, nullptr, ws_X, V);
    // Y = p @ W2^T           (W2 = W_out[:, J:], row stride 2J)
    gemm_nt_kernel<<<dim3(MU / TILE, V / TILE), 256, 0, stream>>>(
        ws_p, MU, J, W_out + J, 2 * J, nullptr, nullptr, ws_Y, V);
    // out = X[bt,:] broadcast+ Y[bu,:]
    bcast_kernel<<<dim3(B * T), 256, 0, stream>>>(ws_X, ws_Y, out, T, U);
}

// Round 2
// 211.088 us; speedup vs baseline: 1.0427x; 1.0427x over previous
//
#include <hip/hip_runtime.h>

typedef float f4 __attribute__((ext_vector_type(4)));
typedef float f32x4 __attribute__((ext_vector_type(4)));
typedef short bf16x8 __attribute__((ext_vector_type(8)));
typedef unsigned short u16x8 __attribute__((ext_vector_type(8)));

static __device__ __forceinline__ unsigned short f2bf(float f) {
    unsigned int x = __builtin_bit_cast(unsigned int, f);
    x = (x + 0x7fffu + ((x >> 16) & 1u)) >> 16;
    return (unsigned short)x;
}
static __device__ __forceinline__ float bf2f(unsigned short h) {
    unsigned int x = ((unsigned int)h) << 16;
    return __builtin_bit_cast(float, x);
}

// ---------------- convert: f32 -> (bf16 hi, bf16 lo) planes, 5 tensors fused
struct CvtJob { const float* src; unsigned short* hi; unsigned short* lo; int n8; };

__global__ __launch_bounds__(256) void convert_kernel(
    CvtJob j0, CvtJob j1, CvtJob j2, CvtJob j3, CvtJob j4, int total8)
{
    CvtJob jobs[5] = { j0, j1, j2, j3, j4 };
    int cum1 = j0.n8, cum2 = cum1 + j1.n8, cum3 = cum2 + j2.n8, cum4 = cum3 + j3.n8;
    for (int g = blockIdx.x * blockDim.x + threadIdx.x; g < total8;
         g += gridDim.x * blockDim.x) {
        int ji, base;
        if      (g < cum1) { ji = 0; base = 0; }
        else if (g < cum2) { ji = 1; base = cum1; }
        else if (g < cum3) { ji = 2; base = cum2; }
        else if (g < cum4) { ji = 3; base = cum3; }
        else               { ji = 4; base = cum4; }
        const CvtJob& J = jobs[ji];
        int idx = (g - base) * 8;
        f4 a = *(const f4*)(J.src + idx);
        f4 b = *(const f4*)(J.src + idx + 4);
        u16x8 hv, lv;
        float s[8] = { a.x, a.y, a.z, a.w, b.x, b.y, b.z, b.w };
        #pragma unroll
        for (int i = 0; i < 8; ++i) {
            unsigned short h = f2bf(s[i]);
            hv[i] = h;
            lv[i] = f2bf(s[i] - bf2f(h));
        }
        *(u16x8*)(J.hi + idx) = hv;
        *(u16x8*)(J.lo + idx) = lv;
    }
}

// ---------------- split-bf16 MFMA GEMM: C[M,N] = A[M,K] @ W[N,K]^T + bias
// A, W given as bf16 hi/lo planes. 128x128 tile, BK=32, 4 waves (2x2 of 64x64).
template<bool SPLIT_OUT>
__global__ __launch_bounds__(256) void gemm_mfma(
    const unsigned short* __restrict__ Ah, const unsigned short* __restrict__ Al,
    int M, int K,
    const unsigned short* __restrict__ Wh, const unsigned short* __restrict__ Wl,
    int ldw,
    const float* __restrict__ bias,
    float* __restrict__ Cf,
    unsigned short* __restrict__ Ch, unsigned short* __restrict__ Cl,
    int N)
{
    __shared__ unsigned short Ah_s[128][40];   // +8 pad: stride 80 B
    __shared__ unsigned short Al_s[128][40];
    __shared__ unsigned short Wh_s[128][40];
    __shared__ unsigned short Wl_s[128][40];

    const int tid  = threadIdx.x;
    const int lane = tid & 63;
    const int wid  = tid >> 6;
    const int wr   = wid >> 1, wc = wid & 1;
    const int m0   = blockIdx.x * 128, n0 = blockIdx.y * 128;

    // staging: 512 16B-chunks per plane, 2 per thread
    const int c0 = tid, c1 = tid + 256;
    const int r0 = c0 >> 2, q0 = (c0 & 3) * 8;
    const int r1 = c1 >> 2, q1 = (c1 & 3) * 8;

    const int lrow = lane & 15;
    const int lk   = (lane >> 4) * 8;

    f32x4 acc[4][4];
    #pragma unroll
    for (int i = 0; i < 4; ++i)
        #pragma unroll
        for (int j = 0; j < 4; ++j) acc[i][j] = (f32x4){0.f, 0.f, 0.f, 0.f};

    for (int k0 = 0; k0 < K; k0 += 32) {
        u16x8 sa0 = *(const u16x8*)(Ah + (size_t)(m0 + r0) * K + k0 + q0);
        u16x8 sa1 = *(const u16x8*)(Ah + (size_t)(m0 + r1) * K + k0 + q1);
        u16x8 sb0 = *(const u16x8*)(Al + (size_t)(m0 + r0) * K + k0 + q0);
        u16x8 sb1 = *(const u16x8*)(Al + (size_t)(m0 + r1) * K + k0 + q1);
        u16x8 sw0 = *(const u16x8*)(Wh + (size_t)(n0 + r0) * ldw + k0 + q0);
        u16x8 sw1 = *(const u16x8*)(Wh + (size_t)(n0 + r1) * ldw + k0 + q1);
        u16x8 sx0 = *(const u16x8*)(Wl + (size_t)(n0 + r0) * ldw + k0 + q0);
        u16x8 sx1 = *(const u16x8*)(Wl + (size_t)(n0 + r1) * ldw + k0 + q1);
        if (k0) __syncthreads();
        *(u16x8*)&Ah_s[r0][q0] = sa0; *(u16x8*)&Ah_s[r1][q1] = sa1;
        *(u16x8*)&Al_s[r0][q0] = sb0; *(u16x8*)&Al_s[r1][q1] = sb1;
        *(u16x8*)&Wh_s[r0][q0] = sw0; *(u16x8*)&Wh_s[r1][q1] = sw1;
        *(u16x8*)&Wl_s[r0][q0] = sx0; *(u16x8*)&Wl_s[r1][q1] = sx1;
        __syncthreads();

        bf16x8 ah[4], al[4], wh[4], wl[4];
        #pragma unroll
        for (int i = 0; i < 4; ++i) {
            ah[i] = *(const bf16x8*)&Ah_s[wr * 64 + i * 16 + lrow][lk];
            al[i] = *(const bf16x8*)&Al_s[wr * 64 + i * 16 + lrow][lk];
            wh[i] = *(const bf16x8*)&Wh_s[wc * 64 + i * 16 + lrow][lk];
            wl[i] = *(const bf16x8*)&Wl_s[wc * 64 + i * 16 + lrow][lk];
        }
        #pragma unroll
        for (int i = 0; i < 4; ++i)
            #pragma unroll
            for (int j = 0; j < 4; ++j) {
                acc[i][j] = __builtin_amdgcn_mfma_f32_16x16x32_bf16(ah[i], wh[j], acc[i][j], 0, 0, 0);
                acc[i][j] = __builtin_amdgcn_mfma_f32_16x16x32_bf16(ah[i], wl[j], acc[i][j], 0, 0, 0);
                acc[i][j] = __builtin_amdgcn_mfma_f32_16x16x32_bf16(al[i], wh[j], acc[i][j], 0, 0, 0);
            }
    }

    // epilogue: C/D layout col=lane&15, row=(lane>>4)*4+r  [m89-verified]
    #pragma unroll
    for (int i = 0; i < 4; ++i) {
        const int rbase = m0 + wr * 64 + i * 16 + (lane >> 4) * 4;
        #pragma unroll
        for (int j = 0; j < 4; ++j) {
            const int col = n0 + wc * 64 + j * 16 + (lane & 15);
            const float bv = bias ? bias[col] : 0.f;
            #pragma unroll
            for (int r = 0; r < 4; ++r) {
                float v = acc[i][j][r] + bv;
                size_t off = (size_t)(rbase + r) * N + col;
                if (SPLIT_OUT) {
                    unsigned short h = f2bf(v);
                    Ch[off] = h;
                    Cl[off] = f2bf(v - bf2f(h));
                } else {
                    Cf[off] = v;
                }
            }
        }
    }
}

// ---------------- broadcast add: out[(b,t),u,:] = X[(b,t),:] + Y[(b,u),:]
__global__ __launch_bounds__(256) void bcast_kernel(
    const float* __restrict__ X, const float* __restrict__ Y,
    float* __restrict__ out, int T, int U)
{
    const int Vq  = 256;           // 1024 / 4
    const int bt  = blockIdx.x;
    const int b   = bt / T;
    const int tid = threadIdx.x;

    const f4* X4 = (const f4*)X;
    const f4* Y4 = (const f4*)Y + (size_t)b * U * Vq;
    f4* O4 = (f4*)out + (size_t)bt * U * Vq;

    f4 x = X4[(size_t)bt * Vq + tid];
    #pragma unroll 4
    for (int u = 0; u < U; ++u) {
        f4 y = Y4[u * Vq + tid];
        f4 r = { x.x + y.x, x.y + y.y, x.z + y.z, x.w + y.w };
        __builtin_nontemporal_store(r, &O4[u * Vq + tid]);
    }
}

extern "C" void kernel_launch(void* const* d_in, const int* in_sizes, int n_in,
                              void* d_out, int out_size, void* d_ws, size_t ws_size,
                              hipStream_t stream) {
    (void)in_sizes; (void)n_in; (void)out_size; (void)ws_size;

    const int B = 8, T = 256, U = 64;
    const int ENC = 512, DEC = 640, J = 512, V = 1024;
    const int MT = B * T;   // 2048
    const int MU = B * U;   // 512

    const float* enc    = (const float*)d_in[0];
    const float* pred   = (const float*)d_in[1];
    const float* W_enc  = (const float*)d_in[2];
    const float* b_enc  = (const float*)d_in[3];
    const float* W_pred = (const float*)d_in[4];
    const float* b_pred = (const float*)d_in[5];
    const float* W_out  = (const float*)d_in[6];
    const float* b_out  = (const float*)d_in[7];
    float* out = (float*)d_out;

    // element counts
    const int n_enc  = MT * ENC;       // 1048576
    const int n_pred = MU * DEC;       // 327680
    const int n_We   = J * ENC;        // 262144
    const int n_Wp   = J * DEC;        // 327680
    const int n_Wo   = V * 2 * J;      // 1048576
    const int n_e    = MT * J;         // 1048576
    const int n_p    = MU * J;         // 262144

    unsigned short* w = (unsigned short*)d_ws;
    unsigned short *enc_h = w, *enc_l;
    enc_l = enc_h + n_enc;
    unsigned short* pred_h = enc_l + n_enc;
    unsigned short* pred_l = pred_h + n_pred;
    unsigned short* We_h   = pred_l + n_pred;
    unsigned short* We_l   = We_h + n_We;
    unsigned short* Wp_h   = We_l + n_We;
    unsigned short* Wp_l   = Wp_h + n_Wp;
    unsigned short* Wo_h   = Wp_l + n_Wp;
    unsigned short* Wo_l   = Wo_h + n_Wo;
    unsigned short* e_h    = Wo_l + n_Wo;
    unsigned short* e_l    = e_h + n_e;
    unsigned short* p_h    = e_l + n_e;
    unsigned short* p_l    = p_h + n_p;
    float* ws_X = (float*)(p_l + n_p);          // (MT, V)
    float* ws_Y = ws_X + (size_t)MT * V;        // (MU, V)

    // 1) convert all f32 inputs to bf16 hi/lo planes
    CvtJob j0 = { enc,    enc_h,  enc_l,  n_enc  / 8 };
    CvtJob j1 = { pred,   pred_h, pred_l, n_pred / 8 };
    CvtJob j2 = { W_enc,  We_h,   We_l,   n_We   / 8 };
    CvtJob j3 = { W_pred, Wp_h,   Wp_l,   n_Wp   / 8 };
    CvtJob j4 = { W_out,  Wo_h,   Wo_l,   n_Wo   / 8 };
    const int total8 = (n_enc + n_pred + n_We + n_Wp + n_Wo) / 8;
    convert_kernel<<<(total8 + 255) / 256, 256, 0, stream>>>(j0, j1, j2, j3, j4, total8);

    // 2) e = enc @ W_enc^T + b_enc   -> bf16 hi/lo
    gemm_mfma<true><<<dim3(MT / 128, J / 128), 256, 0, stream>>>(
        enc_h, enc_l, MT, ENC, We_h, We_l, ENC, b_enc,
        nullptr, e_h, e_l, J);
    // 3) p = pred @ W_pred^T + b_pred -> bf16 hi/lo
    gemm_mfma<true><<<dim3(MU / 128, J / 128), 256, 0, stream>>>(
        pred_h, pred_l, MU, DEC, Wp_h, Wp_l, DEC, b_pred,
        nullptr, p_h, p_l, J);
    // 4) X = e @ W1^T + b_out   (W1 = W_out[:, :J], row stride 2J)
    gemm_mfma<false><<<dim3(MT / 128, V / 128), 256, 0, stream>>>(
        e_h, e_l, MT, J, Wo_h, Wo_l, 2 * J, b_out,
        ws_X, nullptr, nullptr, V);
    // 5) Y = p @ W2^T           (W2 = W_out[:, J:])
    gemm_mfma<false><<<dim3(MU / 128, V / 128), 256, 0, stream>>>(
        p_h, p_l, MU, J, Wo_h + J, Wo_l + J, 2 * J, nullptr,
        ws_Y, nullptr, nullptr, V);

    // 6) out = X broadcast + Y
    bcast_kernel<<<dim3(B * T), 256, 0, stream>>>(ws_X, ws_Y, out, T, U);
}

// Round 3
// 152.840 us; speedup vs baseline: 1.4401x; 1.3811x over previous
//
#include <hip/hip_runtime.h>

typedef float f4 __attribute__((ext_vector_type(4)));
typedef float f32x4 __attribute__((ext_vector_type(4)));
typedef short bf16x8 __attribute__((ext_vector_type(8)));
typedef unsigned short u16x8 __attribute__((ext_vector_type(8)));

static __device__ __forceinline__ unsigned short f2bf(float f) {
    unsigned int x = __builtin_bit_cast(unsigned int, f);
    x = (x + 0x7fffu + ((x >> 16) & 1u)) >> 16;
    return (unsigned short)x;
}
static __device__ __forceinline__ float bf2f(unsigned short h) {
    unsigned int x = ((unsigned int)h) << 16;
    return __builtin_bit_cast(float, x);
}

// ---------------- convert: f32 -> (bf16 hi, bf16 lo) planes, 5 tensors fused
struct CvtJob { const float* src; unsigned short* hi; unsigned short* lo; int n8; };

__global__ __launch_bounds__(256) void convert_kernel(
    CvtJob j0, CvtJob j1, CvtJob j2, CvtJob j3, CvtJob j4, int total8)
{
    CvtJob jobs[5] = { j0, j1, j2, j3, j4 };
    int cum1 = j0.n8, cum2 = cum1 + j1.n8, cum3 = cum2 + j2.n8, cum4 = cum3 + j3.n8;
    for (int g = blockIdx.x * blockDim.x + threadIdx.x; g < total8;
         g += gridDim.x * blockDim.x) {
        int ji, base;
        if      (g < cum1) { ji = 0; base = 0; }
        else if (g < cum2) { ji = 1; base = cum1; }
        else if (g < cum3) { ji = 2; base = cum2; }
        else if (g < cum4) { ji = 3; base = cum3; }
        else               { ji = 4; base = cum4; }
        const CvtJob& J = jobs[ji];
        int idx = (g - base) * 8;
        f4 a = *(const f4*)(J.src + idx);
        f4 b = *(const f4*)(J.src + idx + 4);
        u16x8 hv, lv;
        float s[8] = { a.x, a.y, a.z, a.w, b.x, b.y, b.z, b.w };
        #pragma unroll
        for (int i = 0; i < 8; ++i) {
            unsigned short h = f2bf(s[i]);
            hv[i] = h;
            lv[i] = f2bf(s[i] - bf2f(h));
        }
        *(u16x8*)(J.hi + idx) = hv;
        *(u16x8*)(J.lo + idx) = lv;
    }
}

// ---------------- merged split-bf16 MFMA GEMM, 64x64 tiles, 2 jobs per launch
struct GJob {
    const unsigned short *Ah, *Al, *Wh, *Wl;
    int lda, ldw;
    const float* bias;
    float* Cf;
    unsigned short *Ch, *Cl;
    int N, K, nbx;
};

template<bool SPLIT_OUT>
__global__ __launch_bounds__(256, 2) void gemm64(GJob j0, GJob j1, int nblk0)
{
    __shared__ unsigned short Ah_s[64][40];   // +8 pad
    __shared__ unsigned short Al_s[64][40];
    __shared__ unsigned short Wh_s[64][40];
    __shared__ unsigned short Wl_s[64][40];

    const bool first = (int)blockIdx.x < nblk0;
    const GJob J = first ? j0 : j1;
    const int local = first ? (int)blockIdx.x : (int)blockIdx.x - nblk0;
    const int m0 = (local % J.nbx) * 64;
    const int n0 = (local / J.nbx) * 64;

    const int tid  = threadIdx.x;
    const int lane = tid & 63;
    const int wid  = tid >> 6;
    const int wr   = wid >> 1, wc = wid & 1;
    const int row  = tid >> 2, q = (tid & 3) * 8;
    const int lrow = lane & 15, lk = (lane >> 4) * 8;

    const unsigned short* pAh = J.Ah + (size_t)(m0 + row) * J.lda + q;
    const unsigned short* pAl = J.Al + (size_t)(m0 + row) * J.lda + q;
    const unsigned short* pWh = J.Wh + (size_t)(n0 + row) * J.ldw + q;
    const unsigned short* pWl = J.Wl + (size_t)(n0 + row) * J.ldw + q;

    f32x4 acc[2][2];
    #pragma unroll
    for (int i = 0; i < 2; ++i)
        #pragma unroll
        for (int j = 0; j < 2; ++j) acc[i][j] = (f32x4){0.f, 0.f, 0.f, 0.f};

    for (int k0 = 0; k0 < J.K; k0 += 32) {
        u16x8 ra = *(const u16x8*)(pAh + k0);
        u16x8 rb = *(const u16x8*)(pAl + k0);
        u16x8 rc = *(const u16x8*)(pWh + k0);
        u16x8 rd = *(const u16x8*)(pWl + k0);
        if (k0) __syncthreads();
        *(u16x8*)&Ah_s[row][q] = ra;
        *(u16x8*)&Al_s[row][q] = rb;
        *(u16x8*)&Wh_s[row][q] = rc;
        *(u16x8*)&Wl_s[row][q] = rd;
        __syncthreads();

        bf16x8 ah[2], al[2], wh[2], wl[2];
        #pragma unroll
        for (int i = 0; i < 2; ++i) {
            ah[i] = *(const bf16x8*)&Ah_s[wr * 32 + i * 16 + lrow][lk];
            al[i] = *(const bf16x8*)&Al_s[wr * 32 + i * 16 + lrow][lk];
            wh[i] = *(const bf16x8*)&Wh_s[wc * 32 + i * 16 + lrow][lk];
            wl[i] = *(const bf16x8*)&Wl_s[wc * 32 + i * 16 + lrow][lk];
        }
        #pragma unroll
        for (int i = 0; i < 2; ++i)
            #pragma unroll
            for (int j = 0; j < 2; ++j) {
                acc[i][j] = __builtin_amdgcn_mfma_f32_16x16x32_bf16(ah[i], wh[j], acc[i][j], 0, 0, 0);
                acc[i][j] = __builtin_amdgcn_mfma_f32_16x16x32_bf16(ah[i], wl[j], acc[i][j], 0, 0, 0);
                acc[i][j] = __builtin_amdgcn_mfma_f32_16x16x32_bf16(al[i], wh[j], acc[i][j], 0, 0, 0);
            }
    }

    // C/D layout: col = lane&15, row = (lane>>4)*4 + r
    #pragma unroll
    for (int i = 0; i < 2; ++i) {
        const int rbase = m0 + wr * 32 + i * 16 + (lane >> 4) * 4;
        #pragma unroll
        for (int j = 0; j < 2; ++j) {
            const int col = n0 + wc * 32 + j * 16 + (lane & 15);
            const float bv = J.bias ? J.bias[col] : 0.f;
            #pragma unroll
            for (int r = 0; r < 4; ++r) {
                float v = acc[i][j][r] + bv;
                size_t off = (size_t)(rbase + r) * J.N + col;
                if (SPLIT_OUT) {
                    unsigned short h = f2bf(v);
                    J.Ch[off] = h;
                    J.Cl[off] = f2bf(v - bf2f(h));
                } else {
                    J.Cf[off] = v;
                }
            }
        }
    }
}

// ---------------- broadcast add: out[(b,t),u,:] = X[(b,t),:] + Y[(b,u),:]
__global__ __launch_bounds__(256) void bcast_kernel(
    const float* __restrict__ X, const float* __restrict__ Y,
    float* __restrict__ out, int T, int U)
{
    const int Vq  = 256;           // 1024 / 4
    const int bt  = blockIdx.x;
    const int b   = bt / T;
    const int tid = threadIdx.x;

    const f4* X4 = (const f4*)X;
    const f4* Y4 = (const f4*)Y + (size_t)b * U * Vq;
    f4* O4 = (f4*)out + (size_t)bt * U * Vq;

    f4 x = X4[(size_t)bt * Vq + tid];
    #pragma unroll 4
    for (int u = 0; u < U; ++u) {
        f4 y = Y4[u * Vq + tid];
        f4 r = { x.x + y.x, x.y + y.y, x.z + y.z, x.w + y.w };
        __builtin_nontemporal_store(r, &O4[u * Vq + tid]);
    }
}

extern "C" void kernel_launch(void* const* d_in, const int* in_sizes, int n_in,
                              void* d_out, int out_size, void* d_ws, size_t ws_size,
                              hipStream_t stream) {
    (void)in_sizes; (void)n_in; (void)out_size; (void)ws_size;

    const int B = 8, T = 256, U = 64;
    const int ENC = 512, DEC = 640, J = 512, V = 1024;
    const int MT = B * T;   // 2048
    const int MU = B * U;   // 512

    const float* enc    = (const float*)d_in[0];
    const float* pred   = (const float*)d_in[1];
    const float* W_enc  = (const float*)d_in[2];
    const float* b_enc  = (const float*)d_in[3];
    const float* W_pred = (const float*)d_in[4];
    const float* b_pred = (const float*)d_in[5];
    const float* W_out  = (const float*)d_in[6];
    const float* b_out  = (const float*)d_in[7];
    float* out = (float*)d_out;

    const int n_enc  = MT * ENC;
    const int n_pred = MU * DEC;
    const int n_We   = J * ENC;
    const int n_Wp   = J * DEC;
    const int n_Wo   = V * 2 * J;
    const int n_e    = MT * J;
    const int n_p    = MU * J;

    unsigned short* w = (unsigned short*)d_ws;
    unsigned short* enc_h  = w;
    unsigned short* enc_l  = enc_h + n_enc;
    unsigned short* pred_h = enc_l + n_enc;
    unsigned short* pred_l = pred_h + n_pred;
    unsigned short* We_h   = pred_l + n_pred;
    unsigned short* We_l   = We_h + n_We;
    unsigned short* Wp_h   = We_l + n_We;
    unsigned short* Wp_l   = Wp_h + n_Wp;
    unsigned short* Wo_h   = Wp_l + n_Wp;
    unsigned short* Wo_l   = Wo_h + n_Wo;
    unsigned short* e_h    = Wo_l + n_Wo;
    unsigned short* e_l    = e_h + n_e;
    unsigned short* p_h    = e_l + n_e;
    unsigned short* p_l    = p_h + n_p;
    float* ws_X = (float*)(p_l + n_p);          // (MT, V)
    float* ws_Y = ws_X + (size_t)MT * V;        // (MU, V)

    // 1) convert all f32 inputs to bf16 hi/lo planes
    CvtJob j0 = { enc,    enc_h,  enc_l,  n_enc  / 8 };
    CvtJob j1 = { pred,   pred_h, pred_l, n_pred / 8 };
    CvtJob j2 = { W_enc,  We_h,   We_l,   n_We   / 8 };
    CvtJob j3 = { W_pred, Wp_h,   Wp_l,   n_Wp   / 8 };
    CvtJob j4 = { W_out,  Wo_h,   Wo_l,   n_Wo   / 8 };
    const int total8 = (n_enc + n_pred + n_We + n_Wp + n_Wo) / 8;
    convert_kernel<<<(total8 + 255) / 256, 256, 0, stream>>>(j0, j1, j2, j3, j4, total8);

    // 2) merged e + p GEMMs (split-bf16 planes out)
    GJob je = { enc_h, enc_l, We_h, We_l, ENC, ENC, b_enc,
                nullptr, e_h, e_l, J, ENC, MT / 64 };
    GJob jp = { pred_h, pred_l, Wp_h, Wp_l, DEC, DEC, b_pred,
                nullptr, p_h, p_l, J, DEC, MU / 64 };
    const int nbe = (MT / 64) * (J / 64);   // 256
    const int nbp = (MU / 64) * (J / 64);   // 64
    gemm64<true><<<nbe + nbp, 256, 0, stream>>>(je, jp, nbe);

    // 3) merged X + Y GEMMs (f32 out)
    GJob jx = { e_h, e_l, Wo_h, Wo_l, J, 2 * J, b_out,
                ws_X, nullptr, nullptr, V, J, MT / 64 };
    GJob jy = { p_h, p_l, Wo_h + J, Wo_l + J, J, 2 * J, nullptr,
                ws_Y, nullptr, nullptr, V, J, MU / 64 };
    const int nbx = (MT / 64) * (V / 64);   // 512
    const int nby = (MU / 64) * (V / 64);   // 128
    gemm64<false><<<nbx + nby, 256, 0, stream>>>(jx, jy, nbx);

    // 4) out = X broadcast + Y
    bcast_kernel<<<dim3(B * T), 256, 0, stream>>>(ws_X, ws_Y, out, T, U);
}